// Round 2
// baseline (397.842 us; speedup 1.0000x reference)
//
#include <hip/hip_runtime.h>
#include <hip/hip_bf16.h>

// FourierAttention: x[4,2048,1024] f32; Q/K/V/O projections (nn.Linear: x@W^T+b),
// single-head full attention over d_model=1024, out projection. All inputs/outputs
// f32; internal compute bf16 MFMA (threshold is 2% of max|ref| -> bf16-safe).
//
// Pipeline: convert x,W* to bf16 -> gemm_bt x3 (Q,K,V^T) -> gemm_bt (scores*0.125)
//           -> row softmax (in-place bf16) -> gemm_bt (P @ V via V^T) -> gemm_bt
//           (out proj, f32 store).
// gemm_bt: C[M,N] = A[M,K] * B[N,K]^T  (both K-contiguous) — m97 structure:
// 128x128 tile, BK=32, global_load_lds width=16 staging, 16x16x32 bf16 MFMA.
// Layouts (HW-verified m89/m91): A-frag[m=lane&15][k=(lane>>4)*8+j];
// C/D col=lane&15, row=(lane>>4)*4+reg.

#define TILE 128
#define BK 32

typedef __attribute__((ext_vector_type(8))) short bf16x8;
typedef __attribute__((ext_vector_type(4))) float f32x4;

// mode: 0 = bf16 store (row-major), 1 = bf16 store transposed as V^T[B][D][S],
//       2 = f32 store (row-major)
__global__ __launch_bounds__(256) void gemm_bt(
    const __hip_bfloat16* __restrict__ A,
    const __hip_bfloat16* __restrict__ B,
    void* __restrict__ Cv,
    const float* __restrict__ bias,
    int K, int ldC,
    long sA, long sB, long sC,
    float scale, int mode)
{
  const long z = blockIdx.z;
  const __hip_bfloat16* Ab = A + z * sA;
  const __hip_bfloat16* Bb = B + z * sB;

  __shared__ __hip_bfloat16 As[TILE * BK];   // 8 KB
  __shared__ __hip_bfloat16 Bs[TILE * BK];   // 8 KB

  const int tid  = threadIdx.x;
  const int lane = tid & 63;
  const int wid  = tid >> 6;        // 4 waves
  const int wr   = (wid >> 1) * 64; // wave sub-tile row
  const int wc   = (wid & 1) * 64;  // wave sub-tile col
  const int lr   = lane & 15;
  const int q    = lane >> 4;       // 0..3

  const long rowBase = (long)blockIdx.x * TILE;
  const long colBase = (long)blockIdx.y * TILE;

  f32x4 acc[4][4] = {};

  for (int k0 = 0; k0 < K; k0 += BK) {
    // ---- stage A,B tiles (128 rows x 32 bf16 = 64B/row = 4 x16B segments) ----
    #pragma unroll
    for (int p = 0; p < 2; ++p) {
      int seg = tid + p * 256;          // 0..511
      int r   = seg >> 2;               // tile row
      int cq  = seg & 3;                // 16B chunk in row
      const __hip_bfloat16* ga = Ab + (rowBase + r) * (long)K + k0 + cq * 8;
      __builtin_amdgcn_global_load_lds(
          (const __attribute__((address_space(1))) void*)ga,
          (__attribute__((address_space(3))) void*)(As + seg * 8), 16, 0, 0);
      const __hip_bfloat16* gb = Bb + (colBase + r) * (long)K + k0 + cq * 8;
      __builtin_amdgcn_global_load_lds(
          (const __attribute__((address_space(1))) void*)gb,
          (__attribute__((address_space(3))) void*)(Bs + seg * 8), 16, 0, 0);
    }
    __syncthreads();

    bf16x8 af[4], bfr[4];
    #pragma unroll
    for (int mi = 0; mi < 4; ++mi)
      af[mi] = *(const bf16x8*)(As + (wr + mi * 16 + lr) * BK + q * 8);
    #pragma unroll
    for (int ni = 0; ni < 4; ++ni)
      bfr[ni] = *(const bf16x8*)(Bs + (wc + ni * 16 + lr) * BK + q * 8);

    #pragma unroll
    for (int mi = 0; mi < 4; ++mi)
      #pragma unroll
      for (int ni = 0; ni < 4; ++ni)
        acc[mi][ni] = __builtin_amdgcn_mfma_f32_16x16x32_bf16(
            af[mi], bfr[ni], acc[mi][ni], 0, 0, 0);
    __syncthreads();
  }

  // ---- epilogue: scale, +bias(f32), store ----
  #pragma unroll
  for (int ni = 0; ni < 4; ++ni) {
    long col = colBase + wc + ni * 16 + lr;
    float bv = bias ? bias[col] : 0.0f;
    #pragma unroll
    for (int mi = 0; mi < 4; ++mi) {
      #pragma unroll
      for (int i = 0; i < 4; ++i) {
        long row = rowBase + wr + mi * 16 + q * 4 + i;
        float v = acc[mi][ni][i] * scale + bv;
        if (mode == 0) {
          ((__hip_bfloat16*)Cv)[z * sC + row * (long)ldC + col] = __float2bfloat16(v);
        } else if (mode == 1) {
          // V^T layout [B][D][S]: b*D*S + col*S + s   (S=2048, D=1024)
          long b = row >> 11;
          long s = row & 2047;
          ((__hip_bfloat16*)Cv)[b * (1024L * 2048L) + col * 2048L + s] = __float2bfloat16(v);
        } else {
          ((float*)Cv)[z * sC + row * (long)ldC + col] = v;
        }
      }
    }
  }
}

// f32 -> bf16 conversion, 8 elems/thread, n must be divisible by 2048.
__global__ __launch_bounds__(256) void cvt_f32_bf16(
    const float* __restrict__ in, __hip_bfloat16* __restrict__ out)
{
  long i = ((long)blockIdx.x * 256 + threadIdx.x) * 8;
  float4 a = *(const float4*)(in + i);
  float4 b = *(const float4*)(in + i + 4);
  bf16x8 o;
  o[0] = __builtin_bit_cast(short, __float2bfloat16(a.x));
  o[1] = __builtin_bit_cast(short, __float2bfloat16(a.y));
  o[2] = __builtin_bit_cast(short, __float2bfloat16(a.z));
  o[3] = __builtin_bit_cast(short, __float2bfloat16(a.w));
  o[4] = __builtin_bit_cast(short, __float2bfloat16(b.x));
  o[5] = __builtin_bit_cast(short, __float2bfloat16(b.y));
  o[6] = __builtin_bit_cast(short, __float2bfloat16(b.z));
  o[7] = __builtin_bit_cast(short, __float2bfloat16(b.w));
  *(bf16x8*)(out + i) = o;
}

// In-place row softmax over 2048 bf16 elements. One 256-thread block per row,
// 8 contiguous elems/thread (16B vector load/store).
__global__ __launch_bounds__(256) void softmax_rows(__hip_bfloat16* __restrict__ P)
{
  const int tid  = threadIdx.x;
  const int lane = tid & 63;
  const int wid  = tid >> 6;
  __hip_bfloat16* p = P + (long)blockIdx.x * 2048 + tid * 8;

  bf16x8 v = *(const bf16x8*)p;
  float x[8];
  #pragma unroll
  for (int i = 0; i < 8; ++i)
    x[i] = __uint_as_float(((unsigned)(unsigned short)v[i]) << 16);

  float m = x[0];
  #pragma unroll
  for (int i = 1; i < 8; ++i) m = fmaxf(m, x[i]);
  #pragma unroll
  for (int o = 32; o; o >>= 1) m = fmaxf(m, __shfl_xor(m, o));

  __shared__ float rmax[4], rsum[4];
  if (lane == 0) rmax[wid] = m;
  __syncthreads();
  m = fmaxf(fmaxf(rmax[0], rmax[1]), fmaxf(rmax[2], rmax[3]));

  float e[8], s = 0.0f;
  #pragma unroll
  for (int i = 0; i < 8; ++i) { e[i] = __expf(x[i] - m); s += e[i]; }
  #pragma unroll
  for (int o = 32; o; o >>= 1) s += __shfl_xor(s, o);
  if (lane == 0) rsum[wid] = s;
  __syncthreads();
  s = (rsum[0] + rsum[1]) + (rsum[2] + rsum[3]);

  float inv = 1.0f / s;
  bf16x8 ov;
  #pragma unroll
  for (int i = 0; i < 8; ++i) {
    __hip_bfloat16 h = __float2bfloat16(e[i] * inv);
    ov[i] = __builtin_bit_cast(short, h);
  }
  *(bf16x8*)p = ov;
}

extern "C" void kernel_launch(void* const* d_in, const int* in_sizes, int n_in,
                              void* d_out, int out_size, void* d_ws, size_t ws_size,
                              hipStream_t stream) {
  const float* x  = (const float*)d_in[0];
  const float* Wq = (const float*)d_in[1];
  const float* bq = (const float*)d_in[2];
  const float* Wk = (const float*)d_in[3];
  const float* bk = (const float*)d_in[4];
  const float* Wv = (const float*)d_in[5];
  const float* bv = (const float*)d_in[6];
  const float* Wo = (const float*)d_in[7];
  const float* bo = (const float*)d_in[8];
  float* out = (float*)d_out;

  const long B = 4, S = 2048, D = 1024;
  char* ws = (char*)d_ws;
  __hip_bfloat16* xb  = (__hip_bfloat16*)ws; ws += B * S * D * 2;  // 16.8 MB
  __hip_bfloat16* Wqb = (__hip_bfloat16*)ws; ws += D * D * 2;      //  2.1 MB
  __hip_bfloat16* Wkb = (__hip_bfloat16*)ws; ws += D * D * 2;
  __hip_bfloat16* Wvb = (__hip_bfloat16*)ws; ws += D * D * 2;
  __hip_bfloat16* Wob = (__hip_bfloat16*)ws; ws += D * D * 2;
  __hip_bfloat16* Q   = (__hip_bfloat16*)ws; ws += B * S * D * 2;  // 16.8 MB (aliased by O later)
  __hip_bfloat16* Km  = (__hip_bfloat16*)ws; ws += B * S * D * 2;  // 16.8 MB
  __hip_bfloat16* Vt  = (__hip_bfloat16*)ws; ws += B * D * S * 2;  // 16.8 MB [B][D][S]
  __hip_bfloat16* P   = (__hip_bfloat16*)ws; ws += B * S * S * 2;  // 33.5 MB
  __hip_bfloat16* O   = Q;  // Q dead after scores GEMM
  // total ws: ~109 MB

  dim3 blk(256);
  // f32 -> bf16 conversions
  cvt_f32_bf16<<<dim3(4096), blk, 0, stream>>>(x,  xb);
  cvt_f32_bf16<<<dim3(512),  blk, 0, stream>>>(Wq, Wqb);
  cvt_f32_bf16<<<dim3(512),  blk, 0, stream>>>(Wk, Wkb);
  cvt_f32_bf16<<<dim3(512),  blk, 0, stream>>>(Wv, Wvb);
  cvt_f32_bf16<<<dim3(512),  blk, 0, stream>>>(Wo, Wob);

  // Q/K/V projections: M=8192, N=1024, K=1024
  gemm_bt<<<dim3(64, 8, 1), blk, 0, stream>>>(xb, Wqb, Q,  bq, 1024, 1024, 0, 0, 0, 1.0f, 0);
  gemm_bt<<<dim3(64, 8, 1), blk, 0, stream>>>(xb, Wkb, Km, bk, 1024, 1024, 0, 0, 0, 1.0f, 0);
  gemm_bt<<<dim3(64, 8, 1), blk, 0, stream>>>(xb, Wvb, Vt, bv, 1024, 0,    0, 0, 0, 1.0f, 1);
  // scores = Q K^T * 0.125, batched: M=N=2048, K=1024
  gemm_bt<<<dim3(16, 16, 4), blk, 0, stream>>>(Q, Km, P, nullptr, 1024, 2048,
                                               S * D, S * D, S * S, 0.125f, 0);
  // softmax over each of 4*2048 rows
  softmax_rows<<<dim3(8192), blk, 0, stream>>>(P);
  // O = P V  (via V^T rows): M=2048, N=1024, K=2048, batched
  gemm_bt<<<dim3(16, 8, 4), blk, 0, stream>>>(P, Vt, O, nullptr, 2048, 1024,
                                              S * S, D * S, S * D, 1.0f, 0);
  // out = O Wo^T + bo: M=8192, N=1024, K=1024, f32 store
  gemm_bt<<<dim3(64, 8, 1), blk, 0, stream>>>(O, Wob, out, bo, 1024, 1024, 0, 0, 0, 1.0f, 2);
}

// Round 3
// 358.563 us; speedup vs baseline: 1.1095x; 1.1095x over previous
//
#include <hip/hip_runtime.h>
#include <hip/hip_bf16.h>

// FourierAttention: x[4,2048,1024] f32; fused QKV projection (nn.Linear: x@W^T+b),
// single-head full attention over d_model=1024, out projection. Inputs/outputs f32;
// internal compute bf16 MFMA (passes at absmax ~2.9e-3 vs 5.9e-3 threshold).
//
// Pipeline: convert x,W* to bf16 (W q/k/v packed into one [3072,1024])
//   -> gemm_qkv (M=8192,N=3072: writes Q, K, V^T in one pass)
//   -> gemm_bt (scores*0.125) -> row softmax (in-place bf16)
//   -> gemm_bt (P @ V via V^T) -> gemm_bt (out proj, f32 store).
// gemm core: C[M,N] = A[M,K] * B[N,K]^T (both K-contiguous) — m97 structure:
// 128x128 tile, BK=32, global_load_lds width=16 staging, 16x16x32 bf16 MFMA.
// Layouts (HW-verified m89/m91): A-frag[m=lane&15][k=(lane>>4)*8+j];
// C/D col=lane&15, row=(lane>>4)*4+reg.

#define TILE 128
#define BK 32

typedef __attribute__((ext_vector_type(8))) short bf16x8;
typedef __attribute__((ext_vector_type(4))) float f32x4;

// ---------------- shared inner loop as a macro-free helper ----------------
__device__ __forceinline__ void gemm_core(
    const __hip_bfloat16* __restrict__ Ab, const __hip_bfloat16* __restrict__ Bb,
    __hip_bfloat16* As, __hip_bfloat16* Bs,
    long rowBase, long colBase, int K, int tid, int wr, int wc, int lr, int q,
    f32x4 acc[4][4])
{
  for (int k0 = 0; k0 < K; k0 += BK) {
    // stage A,B tiles (128 rows x 32 bf16 = 64B/row = 4 x16B segments)
    #pragma unroll
    for (int p = 0; p < 2; ++p) {
      int seg = tid + p * 256;          // 0..511
      int r   = seg >> 2;               // tile row
      int cq  = seg & 3;                // 16B chunk in row
      const __hip_bfloat16* ga = Ab + (rowBase + r) * (long)K + k0 + cq * 8;
      __builtin_amdgcn_global_load_lds(
          (const __attribute__((address_space(1))) void*)ga,
          (__attribute__((address_space(3))) void*)(As + seg * 8), 16, 0, 0);
      const __hip_bfloat16* gb = Bb + (colBase + r) * (long)K + k0 + cq * 8;
      __builtin_amdgcn_global_load_lds(
          (const __attribute__((address_space(1))) void*)gb,
          (__attribute__((address_space(3))) void*)(Bs + seg * 8), 16, 0, 0);
    }
    __syncthreads();

    bf16x8 af[4], bfr[4];
    #pragma unroll
    for (int mi = 0; mi < 4; ++mi)
      af[mi] = *(const bf16x8*)(As + (wr + mi * 16 + lr) * BK + q * 8);
    #pragma unroll
    for (int ni = 0; ni < 4; ++ni)
      bfr[ni] = *(const bf16x8*)(Bs + (wc + ni * 16 + lr) * BK + q * 8);

    #pragma unroll
    for (int mi = 0; mi < 4; ++mi)
      #pragma unroll
      for (int ni = 0; ni < 4; ++ni)
        acc[mi][ni] = __builtin_amdgcn_mfma_f32_16x16x32_bf16(
            af[mi], bfr[ni], acc[mi][ni], 0, 0, 0);
    __syncthreads();
  }
}

// ---------------- generic GEMM (scores / PV / out-proj) ----------------
// mode: 0 = bf16 store (row-major), 2 = f32 store (row-major)
__global__ __launch_bounds__(256) void gemm_bt(
    const __hip_bfloat16* __restrict__ A,
    const __hip_bfloat16* __restrict__ B,
    void* __restrict__ Cv,
    const float* __restrict__ bias,
    int K, int ldC,
    long sA, long sB, long sC,
    float scale, int mode)
{
  const long z = blockIdx.z;
  __shared__ __hip_bfloat16 As[TILE * BK];
  __shared__ __hip_bfloat16 Bs[TILE * BK];

  const int tid  = threadIdx.x;
  const int lane = tid & 63;
  const int wid  = tid >> 6;
  const int wr   = (wid >> 1) * 64;
  const int wc   = (wid & 1) * 64;
  const int lr   = lane & 15;
  const int q    = lane >> 4;

  const long rowBase = (long)blockIdx.x * TILE;
  const long colBase = (long)blockIdx.y * TILE;

  f32x4 acc[4][4] = {};
  gemm_core(A + z * sA, B + z * sB, As, Bs, rowBase, colBase, K,
            tid, wr, wc, lr, q, acc);

  #pragma unroll
  for (int ni = 0; ni < 4; ++ni) {
    long col = colBase + wc + ni * 16 + lr;
    float bv = bias ? bias[col] : 0.0f;
    #pragma unroll
    for (int mi = 0; mi < 4; ++mi) {
      #pragma unroll
      for (int i = 0; i < 4; ++i) {
        long row = rowBase + wr + mi * 16 + q * 4 + i;
        float v = acc[mi][ni][i] * scale + bv;
        if (mode == 0)
          ((__hip_bfloat16*)Cv)[z * sC + row * (long)ldC + col] = __float2bfloat16(v);
        else
          ((float*)Cv)[z * sC + row * (long)ldC + col] = v;
      }
    }
  }
}

// ---------------- fused QKV projection ----------------
// A = xb[8192,1024], B = Wqkvb[3072,1024] (rows 0-1023 Wq, 1024-2047 Wk, 2048-3071 Wv).
// Col group (block-uniform): 0 -> Q[8192,1024], 1 -> K[8192,1024],
// 2 -> V^T[B=4][D=1024][S=2048] (transposed scatter store).
__global__ __launch_bounds__(256) void gemm_qkv(
    const __hip_bfloat16* __restrict__ A,
    const __hip_bfloat16* __restrict__ B,
    __hip_bfloat16* __restrict__ Q,
    __hip_bfloat16* __restrict__ Kd,
    __hip_bfloat16* __restrict__ Vt,
    const float* __restrict__ bq,
    const float* __restrict__ bk,
    const float* __restrict__ bv)
{
  __shared__ __hip_bfloat16 As[TILE * BK];
  __shared__ __hip_bfloat16 Bs[TILE * BK];

  const int tid  = threadIdx.x;
  const int lane = tid & 63;
  const int wid  = tid >> 6;
  const int wr   = (wid >> 1) * 64;
  const int wc   = (wid & 1) * 64;
  const int lr   = lane & 15;
  const int q    = lane >> 4;

  const long rowBase = (long)blockIdx.x * TILE;
  const long colBase = (long)blockIdx.y * TILE;
  const int K = 1024;

  f32x4 acc[4][4] = {};
  gemm_core(A, B, As, Bs, rowBase, colBase, K, tid, wr, wc, lr, q, acc);

  const int cg = (int)(colBase >> 10);  // 0=Q, 1=K, 2=V (block-uniform)
  const float* bias = (cg == 0) ? bq : ((cg == 1) ? bk : bv);

  #pragma unroll
  for (int ni = 0; ni < 4; ++ni) {
    long col  = colBase + wc + ni * 16 + lr;   // 0..3071
    long colL = col & 1023;
    float bvv = bias[colL];
    #pragma unroll
    for (int mi = 0; mi < 4; ++mi) {
      #pragma unroll
      for (int i = 0; i < 4; ++i) {
        long row = rowBase + wr + mi * 16 + q * 4 + i;   // 0..8191
        float v = acc[mi][ni][i] + bvv;
        __hip_bfloat16 h = __float2bfloat16(v);
        if (cg == 0) {
          Q[row * 1024 + colL] = h;
        } else if (cg == 1) {
          Kd[row * 1024 + colL] = h;
        } else {
          long b = row >> 11, s = row & 2047;
          Vt[b * (1024L * 2048L) + colL * 2048L + s] = h;
        }
      }
    }
  }
}

// f32 -> bf16 conversion, 8 elems/thread.
__global__ __launch_bounds__(256) void cvt_f32_bf16(
    const float* __restrict__ in, __hip_bfloat16* __restrict__ out)
{
  long i = ((long)blockIdx.x * 256 + threadIdx.x) * 8;
  float4 a = *(const float4*)(in + i);
  float4 b = *(const float4*)(in + i + 4);
  bf16x8 o;
  o[0] = __builtin_bit_cast(short, __float2bfloat16(a.x));
  o[1] = __builtin_bit_cast(short, __float2bfloat16(a.y));
  o[2] = __builtin_bit_cast(short, __float2bfloat16(a.z));
  o[3] = __builtin_bit_cast(short, __float2bfloat16(a.w));
  o[4] = __builtin_bit_cast(short, __float2bfloat16(b.x));
  o[5] = __builtin_bit_cast(short, __float2bfloat16(b.y));
  o[6] = __builtin_bit_cast(short, __float2bfloat16(b.z));
  o[7] = __builtin_bit_cast(short, __float2bfloat16(b.w));
  *(bf16x8*)(out + i) = o;
}

// In-place row softmax over 2048 bf16 elements. One 256-thread block per row.
__global__ __launch_bounds__(256) void softmax_rows(__hip_bfloat16* __restrict__ P)
{
  const int tid  = threadIdx.x;
  const int lane = tid & 63;
  const int wid  = tid >> 6;
  __hip_bfloat16* p = P + (long)blockIdx.x * 2048 + tid * 8;

  bf16x8 v = *(const bf16x8*)p;
  float x[8];
  #pragma unroll
  for (int i = 0; i < 8; ++i)
    x[i] = __uint_as_float(((unsigned)(unsigned short)v[i]) << 16);

  float m = x[0];
  #pragma unroll
  for (int i = 1; i < 8; ++i) m = fmaxf(m, x[i]);
  #pragma unroll
  for (int o = 32; o; o >>= 1) m = fmaxf(m, __shfl_xor(m, o));

  __shared__ float rmax[4], rsum[4];
  if (lane == 0) rmax[wid] = m;
  __syncthreads();
  m = fmaxf(fmaxf(rmax[0], rmax[1]), fmaxf(rmax[2], rmax[3]));

  float e[8], s = 0.0f;
  #pragma unroll
  for (int i = 0; i < 8; ++i) { e[i] = __expf(x[i] - m); s += e[i]; }
  #pragma unroll
  for (int o = 32; o; o >>= 1) s += __shfl_xor(s, o);
  if (lane == 0) rsum[wid] = s;
  __syncthreads();
  s = (rsum[0] + rsum[1]) + (rsum[2] + rsum[3]);

  float inv = 1.0f / s;
  bf16x8 ov;
  #pragma unroll
  for (int i = 0; i < 8; ++i) {
    __hip_bfloat16 h = __float2bfloat16(e[i] * inv);
    ov[i] = __builtin_bit_cast(short, h);
  }
  *(bf16x8*)p = ov;
}

extern "C" void kernel_launch(void* const* d_in, const int* in_sizes, int n_in,
                              void* d_out, int out_size, void* d_ws, size_t ws_size,
                              hipStream_t stream) {
  const float* x  = (const float*)d_in[0];
  const float* Wq = (const float*)d_in[1];
  const float* bq = (const float*)d_in[2];
  const float* Wk = (const float*)d_in[3];
  const float* bk = (const float*)d_in[4];
  const float* Wv = (const float*)d_in[5];
  const float* bv = (const float*)d_in[6];
  const float* Wo = (const float*)d_in[7];
  const float* bo = (const float*)d_in[8];
  float* out = (float*)d_out;

  const long B = 4, S = 2048, D = 1024;
  char* ws = (char*)d_ws;
  __hip_bfloat16* xb    = (__hip_bfloat16*)ws; ws += B * S * D * 2;  // 16.8 MB
  __hip_bfloat16* Wqkvb = (__hip_bfloat16*)ws; ws += 3 * D * D * 2;  //  6.3 MB
  __hip_bfloat16* Wob   = (__hip_bfloat16*)ws; ws += D * D * 2;      //  2.1 MB
  __hip_bfloat16* Q     = (__hip_bfloat16*)ws; ws += B * S * D * 2;  // 16.8 MB (O aliases later)
  __hip_bfloat16* Km    = (__hip_bfloat16*)ws; ws += B * S * D * 2;  // 16.8 MB
  __hip_bfloat16* Vt    = (__hip_bfloat16*)ws; ws += B * D * S * 2;  // 16.8 MB [B][D][S]
  __hip_bfloat16* P     = (__hip_bfloat16*)ws; ws += B * S * S * 2;  // 33.5 MB
  __hip_bfloat16* O     = Q;  // Q dead after scores GEMM

  dim3 blk(256);
  // f32 -> bf16 conversions (Wq/Wk/Wv packed row-wise into Wqkvb)
  cvt_f32_bf16<<<dim3(4096), blk, 0, stream>>>(x,  xb);
  cvt_f32_bf16<<<dim3(512),  blk, 0, stream>>>(Wq, Wqkvb);
  cvt_f32_bf16<<<dim3(512),  blk, 0, stream>>>(Wk, Wqkvb + D * D);
  cvt_f32_bf16<<<dim3(512),  blk, 0, stream>>>(Wv, Wqkvb + 2 * D * D);
  cvt_f32_bf16<<<dim3(512),  blk, 0, stream>>>(Wo, Wob);

  // fused QKV projection: M=8192, N=3072, K=1024
  gemm_qkv<<<dim3(64, 24, 1), blk, 0, stream>>>(xb, Wqkvb, Q, Km, Vt, bq, bk, bv);
  // scores = Q K^T * 0.125, batched: M=N=2048, K=1024
  gemm_bt<<<dim3(16, 16, 4), blk, 0, stream>>>(Q, Km, P, nullptr, 1024, 2048,
                                               S * D, S * D, S * S, 0.125f, 0);
  // softmax over each of 4*2048 rows
  softmax_rows<<<dim3(8192), blk, 0, stream>>>(P);
  // O = P V (via V^T rows): M=2048, N=1024, K=2048, batched
  gemm_bt<<<dim3(16, 8, 4), blk, 0, stream>>>(P, Vt, O, nullptr, 2048, 1024,
                                              S * S, D * S, S * D, 1.0f, 0);
  // out = O Wo^T + bo: M=8192, N=1024, K=1024, f32 store
  gemm_bt<<<dim3(64, 8, 1), blk, 0, stream>>>(O, Wob, out, bo, 1024, 1024, 0, 0, 0, 1.0f, 2);
}

// Round 4
// 341.228 us; speedup vs baseline: 1.1659x; 1.0508x over previous
//
#include <hip/hip_runtime.h>
#include <hip/hip_bf16.h>

// FourierAttention: x[4,2048,1024] f32; single-head attention over d_model=1024.
// Algebra: out = P·(x·Wvo^T) + (Wo·bv + bo), Wvo = Wo·Wv  (softmax rows sum to 1,
// so the V-bias passes through P exactly). This removes the out-proj GEMM.
//
// Pipeline: cvt x,Wq,Wk,Wo (f32->bf16), transpose-cvt Wv -> Wvt
//   -> gemm_bt (Wvo = Wo·Wv via Wvt, into QKV weight slot 2) -> bias_vo (f32)
//   -> gemm_qkv (M=8192,N=3072: writes Q, K, VWo^T in one pass)
//   -> gemm_bt (scores*0.125) -> row softmax (in-place bf16)
//   -> gemm_bt (out = P·VWo + bfinal, f32 store).
// GEMM core: C[M,N] = A[M,K]·B[N,K]^T, 128x128 tile, BK=32, 16x16x32 bf16 MFMA,
// double-buffered LDS: one barrier/iter, next tile's global_load_lds issued
// before current tile's ds_read/MFMA so the vmcnt(0) drain overlaps compute.

#define TILE 128
#define BK 32
#define BUFE (TILE * BK)   // elements per LDS buffer

typedef __attribute__((ext_vector_type(8))) short bf16x8;
typedef __attribute__((ext_vector_type(4))) float f32x4;

__device__ __forceinline__ void stage_tiles(
    const __hip_bfloat16* __restrict__ Ab, const __hip_bfloat16* __restrict__ Bb,
    __hip_bfloat16* As, __hip_bfloat16* Bs,
    long rowBase, long colBase, int K, int k0, int tid)
{
  #pragma unroll
  for (int p = 0; p < 2; ++p) {
    int seg = tid + p * 256;          // 0..511
    int r   = seg >> 2;               // tile row
    int cq  = seg & 3;                // 16B chunk in row
    const __hip_bfloat16* ga = Ab + (rowBase + r) * (long)K + k0 + cq * 8;
    __builtin_amdgcn_global_load_lds(
        (const __attribute__((address_space(1))) void*)ga,
        (__attribute__((address_space(3))) void*)(As + seg * 8), 16, 0, 0);
    const __hip_bfloat16* gb = Bb + (colBase + r) * (long)K + k0 + cq * 8;
    __builtin_amdgcn_global_load_lds(
        (const __attribute__((address_space(1))) void*)gb,
        (__attribute__((address_space(3))) void*)(Bs + seg * 8), 16, 0, 0);
  }
}

// As/Bs are [2][BUFE] double buffers.
__device__ __forceinline__ void gemm_core(
    const __hip_bfloat16* __restrict__ Ab, const __hip_bfloat16* __restrict__ Bb,
    __hip_bfloat16* As, __hip_bfloat16* Bs,
    long rowBase, long colBase, int K, int tid, int wr, int wc, int lr, int q,
    f32x4 acc[4][4])
{
  stage_tiles(Ab, Bb, As, Bs, rowBase, colBase, K, 0, tid);
  int buf = 0;
  for (int k0 = 0; k0 < K; k0 += BK, buf ^= 1) {
    __syncthreads();   // drains tile-k loads (issued one iter ago) + read/write hazard
    if (k0 + BK < K)
      stage_tiles(Ab, Bb, As + (buf ^ 1) * BUFE, Bs + (buf ^ 1) * BUFE,
                  rowBase, colBase, K, k0 + BK, tid);

    const __hip_bfloat16* Ac = As + buf * BUFE;
    const __hip_bfloat16* Bc = Bs + buf * BUFE;
    bf16x8 af[4], bfr[4];
    #pragma unroll
    for (int mi = 0; mi < 4; ++mi)
      af[mi] = *(const bf16x8*)(Ac + (wr + mi * 16 + lr) * BK + q * 8);
    #pragma unroll
    for (int ni = 0; ni < 4; ++ni)
      bfr[ni] = *(const bf16x8*)(Bc + (wc + ni * 16 + lr) * BK + q * 8);

    #pragma unroll
    for (int mi = 0; mi < 4; ++mi)
      #pragma unroll
      for (int ni = 0; ni < 4; ++ni)
        acc[mi][ni] = __builtin_amdgcn_mfma_f32_16x16x32_bf16(
            af[mi], bfr[ni], acc[mi][ni], 0, 0, 0);
  }
}

// ---------------- generic GEMM ----------------
// mode: 0 = bf16 store (row-major), 2 = f32 store (row-major)
__global__ __launch_bounds__(256) void gemm_bt(
    const __hip_bfloat16* __restrict__ A,
    const __hip_bfloat16* __restrict__ B,
    void* __restrict__ Cv,
    const float* __restrict__ bias,
    int K, int ldC,
    long sA, long sB, long sC,
    float scale, int mode)
{
  const long z = blockIdx.z;
  __shared__ __hip_bfloat16 As[2 * BUFE];
  __shared__ __hip_bfloat16 Bs[2 * BUFE];

  const int tid  = threadIdx.x;
  const int lane = tid & 63;
  const int wid  = tid >> 6;
  const int wr   = (wid >> 1) * 64;
  const int wc   = (wid & 1) * 64;
  const int lr   = lane & 15;
  const int q    = lane >> 4;

  const long rowBase = (long)blockIdx.x * TILE;
  const long colBase = (long)blockIdx.y * TILE;

  f32x4 acc[4][4] = {};
  gemm_core(A + z * sA, B + z * sB, As, Bs, rowBase, colBase, K,
            tid, wr, wc, lr, q, acc);

  #pragma unroll
  for (int ni = 0; ni < 4; ++ni) {
    long col = colBase + wc + ni * 16 + lr;
    float bv = bias ? bias[col] : 0.0f;
    #pragma unroll
    for (int mi = 0; mi < 4; ++mi) {
      #pragma unroll
      for (int i = 0; i < 4; ++i) {
        long row = rowBase + wr + mi * 16 + q * 4 + i;
        float v = acc[mi][ni][i] * scale + bv;
        if (mode == 0)
          ((__hip_bfloat16*)Cv)[z * sC + row * (long)ldC + col] = __float2bfloat16(v);
        else
          ((float*)Cv)[z * sC + row * (long)ldC + col] = v;
      }
    }
  }
}

// ---------------- fused QKV projection (V-slot carries Wvo) ----------------
// A = xb[8192,1024], B = Wqkvb[3072,1024] (Wq | Wk | Wvo). Col group (block-
// uniform): 0 -> Q[8192,1024] (+bq), 1 -> K[8192,1024] (+bk),
// 2 -> VWo^T[B=4][D=1024][S=2048], NO bias (bias folded into bfinal).
__global__ __launch_bounds__(256) void gemm_qkv(
    const __hip_bfloat16* __restrict__ A,
    const __hip_bfloat16* __restrict__ B,
    __hip_bfloat16* __restrict__ Q,
    __hip_bfloat16* __restrict__ Kd,
    __hip_bfloat16* __restrict__ Vt,
    const float* __restrict__ bq,
    const float* __restrict__ bk)
{
  __shared__ __hip_bfloat16 As[2 * BUFE];
  __shared__ __hip_bfloat16 Bs[2 * BUFE];

  const int tid  = threadIdx.x;
  const int lane = tid & 63;
  const int wid  = tid >> 6;
  const int wr   = (wid >> 1) * 64;
  const int wc   = (wid & 1) * 64;
  const int lr   = lane & 15;
  const int q    = lane >> 4;

  const long rowBase = (long)blockIdx.x * TILE;
  const long colBase = (long)blockIdx.y * TILE;

  f32x4 acc[4][4] = {};
  gemm_core(A, B, As, Bs, rowBase, colBase, 1024, tid, wr, wc, lr, q, acc);

  const int cg = (int)(colBase >> 10);  // 0=Q, 1=K, 2=VWo (block-uniform)

  #pragma unroll
  for (int ni = 0; ni < 4; ++ni) {
    long col  = colBase + wc + ni * 16 + lr;   // 0..3071
    long colL = col & 1023;
    float bvv = (cg == 0) ? bq[colL] : ((cg == 1) ? bk[colL] : 0.0f);
    #pragma unroll
    for (int mi = 0; mi < 4; ++mi) {
      #pragma unroll
      for (int i = 0; i < 4; ++i) {
        long row = rowBase + wr + mi * 16 + q * 4 + i;   // 0..8191
        __hip_bfloat16 h = __float2bfloat16(acc[mi][ni][i] + bvv);
        if (cg == 0) {
          Q[row * 1024 + colL] = h;
        } else if (cg == 1) {
          Kd[row * 1024 + colL] = h;
        } else {
          long b = row >> 11, s = row & 2047;
          Vt[b * (1024L * 2048L) + colL * 2048L + s] = h;
        }
      }
    }
  }
}

// f32 -> bf16 conversion, 8 elems/thread.
__global__ __launch_bounds__(256) void cvt_f32_bf16(
    const float* __restrict__ in, __hip_bfloat16* __restrict__ out)
{
  long i = ((long)blockIdx.x * 256 + threadIdx.x) * 8;
  float4 a = *(const float4*)(in + i);
  float4 b = *(const float4*)(in + i + 4);
  bf16x8 o;
  o[0] = __builtin_bit_cast(short, __float2bfloat16(a.x));
  o[1] = __builtin_bit_cast(short, __float2bfloat16(a.y));
  o[2] = __builtin_bit_cast(short, __float2bfloat16(a.z));
  o[3] = __builtin_bit_cast(short, __float2bfloat16(a.w));
  o[4] = __builtin_bit_cast(short, __float2bfloat16(b.x));
  o[5] = __builtin_bit_cast(short, __float2bfloat16(b.y));
  o[6] = __builtin_bit_cast(short, __float2bfloat16(b.z));
  o[7] = __builtin_bit_cast(short, __float2bfloat16(b.w));
  *(bf16x8*)(out + i) = o;
}

// Transpose-convert: in f32 [1024][1024] -> out bf16 [1024][1024] transposed.
// 64x64 tiles via LDS.
__global__ __launch_bounds__(256) void cvt_t_f32_bf16(
    const float* __restrict__ in, __hip_bfloat16* __restrict__ out)
{
  __shared__ __hip_bfloat16 t[64][65];
  const int tid = threadIdx.x;
  const long rb = (long)blockIdx.y * 64;   // input row base
  const long cb = (long)blockIdx.x * 64;   // input col base
  const int r0 = tid >> 4;        // 0..15
  const int c0 = (tid & 15) * 4;  // 0,4,..,60
  #pragma unroll
  for (int p = 0; p < 4; ++p) {
    int r = r0 + p * 16;
    float4 v = *(const float4*)(in + (rb + r) * 1024 + cb + c0);
    t[c0 + 0][r] = __float2bfloat16(v.x);
    t[c0 + 1][r] = __float2bfloat16(v.y);
    t[c0 + 2][r] = __float2bfloat16(v.z);
    t[c0 + 3][r] = __float2bfloat16(v.w);
  }
  __syncthreads();
  #pragma unroll
  for (int p = 0; p < 4; ++p) {
    int r = r0 + p * 16;   // out-row within tile (= input col)
    __hip_bfloat16* o = out + (cb + r) * 1024 + rb + c0;
    o[0] = t[r][c0 + 0]; o[1] = t[r][c0 + 1];
    o[2] = t[r][c0 + 2]; o[3] = t[r][c0 + 3];
  }
}

// bfinal[e] = dot(Wo[e,:], bv) + bo[e]  (f32, one wave per output)
__global__ __launch_bounds__(256) void bias_vo(
    const float* __restrict__ Wo, const float* __restrict__ bv,
    const float* __restrict__ bo, float* __restrict__ bfinal)
{
  int e = blockIdx.x * 4 + (threadIdx.x >> 6);
  int lane = threadIdx.x & 63;
  const float* row = Wo + (long)e * 1024;
  float s = 0.0f;
  #pragma unroll
  for (int p = 0; p < 4; ++p) {
    float4 w = *(const float4*)(row + p * 256 + lane * 4);
    float4 b = *(const float4*)(bv + p * 256 + lane * 4);
    s += w.x * b.x + w.y * b.y + w.z * b.z + w.w * b.w;
  }
  #pragma unroll
  for (int o = 32; o; o >>= 1) s += __shfl_xor(s, o);
  if (lane == 0) bfinal[e] = s + bo[e];
}

// In-place row softmax over 2048 bf16 elements. One 256-thread block per row.
__global__ __launch_bounds__(256) void softmax_rows(__hip_bfloat16* __restrict__ P)
{
  const int tid  = threadIdx.x;
  const int lane = tid & 63;
  const int wid  = tid >> 6;
  __hip_bfloat16* p = P + (long)blockIdx.x * 2048 + tid * 8;

  bf16x8 v = *(const bf16x8*)p;
  float x[8];
  #pragma unroll
  for (int i = 0; i < 8; ++i)
    x[i] = __uint_as_float(((unsigned)(unsigned short)v[i]) << 16);

  float m = x[0];
  #pragma unroll
  for (int i = 1; i < 8; ++i) m = fmaxf(m, x[i]);
  #pragma unroll
  for (int o = 32; o; o >>= 1) m = fmaxf(m, __shfl_xor(m, o));

  __shared__ float rmax[4], rsum[4];
  if (lane == 0) rmax[wid] = m;
  __syncthreads();
  m = fmaxf(fmaxf(rmax[0], rmax[1]), fmaxf(rmax[2], rmax[3]));

  float e[8], s = 0.0f;
  #pragma unroll
  for (int i = 0; i < 8; ++i) { e[i] = __expf(x[i] - m); s += e[i]; }
  #pragma unroll
  for (int o = 32; o; o >>= 1) s += __shfl_xor(s, o);
  if (lane == 0) rsum[wid] = s;
  __syncthreads();
  s = (rsum[0] + rsum[1]) + (rsum[2] + rsum[3]);

  float inv = 1.0f / s;
  bf16x8 ov;
  #pragma unroll
  for (int i = 0; i < 8; ++i) {
    __hip_bfloat16 h = __float2bfloat16(e[i] * inv);
    ov[i] = __builtin_bit_cast(short, h);
  }
  *(bf16x8*)p = ov;
}

extern "C" void kernel_launch(void* const* d_in, const int* in_sizes, int n_in,
                              void* d_out, int out_size, void* d_ws, size_t ws_size,
                              hipStream_t stream) {
  const float* x  = (const float*)d_in[0];
  const float* Wq = (const float*)d_in[1];
  const float* bq = (const float*)d_in[2];
  const float* Wk = (const float*)d_in[3];
  const float* bk = (const float*)d_in[4];
  const float* Wv = (const float*)d_in[5];
  const float* bv = (const float*)d_in[6];
  const float* Wo = (const float*)d_in[7];
  const float* bo = (const float*)d_in[8];
  float* out = (float*)d_out;

  const long B = 4, S = 2048, D = 1024;
  char* ws = (char*)d_ws;
  __hip_bfloat16* xb    = (__hip_bfloat16*)ws; ws += B * S * D * 2;  // 16.8 MB
  __hip_bfloat16* Wqkvb = (__hip_bfloat16*)ws; ws += 3 * D * D * 2;  //  6.3 MB (Wq|Wk|Wvo)
  __hip_bfloat16* Wob   = (__hip_bfloat16*)ws; ws += D * D * 2;      //  2.1 MB
  __hip_bfloat16* Q     = (__hip_bfloat16*)ws; ws += B * S * D * 2;  // 16.8 MB
  __hip_bfloat16* Km    = (__hip_bfloat16*)ws; ws += B * S * D * 2;  // 16.8 MB
  __hip_bfloat16* VWot  = (__hip_bfloat16*)ws; ws += B * D * S * 2;  // 16.8 MB [B][D][S]
  __hip_bfloat16* P     = (__hip_bfloat16*)ws; ws += B * S * S * 2;  // 33.5 MB
  // Aliases (dead-region reuse, keeps ws at ~109 MB):
  __hip_bfloat16* Wvtb   = Q;            // Wv^T bf16, dead before gemm_qkv writes Q
  float*          bfinal = (float*)Wob;  // overwrites Wob AFTER the Wvo GEMM reads it

  dim3 blk(256);
  // converts
  cvt_f32_bf16<<<dim3(4096), blk, 0, stream>>>(x,  xb);
  cvt_f32_bf16<<<dim3(512),  blk, 0, stream>>>(Wq, Wqkvb);
  cvt_f32_bf16<<<dim3(512),  blk, 0, stream>>>(Wk, Wqkvb + D * D);
  cvt_f32_bf16<<<dim3(512),  blk, 0, stream>>>(Wo, Wob);
  cvt_t_f32_bf16<<<dim3(16, 16), blk, 0, stream>>>(Wv, Wvtb);

  // Wvo = Wo · Wv  (via Wv^T, K-contiguous both sides) -> QKV weight slot 2
  gemm_bt<<<dim3(8, 8, 1), blk, 0, stream>>>(Wob, Wvtb, Wqkvb + 2 * D * D,
                                             nullptr, 1024, 1024, 0, 0, 0, 1.0f, 0);
  // bfinal = Wo·bv + bo  (f32) — overwrites Wob region (safe: after Wvo GEMM)
  bias_vo<<<dim3(256), blk, 0, stream>>>(Wo, bv, bo, bfinal);

  // fused QKV projection: M=8192, N=3072, K=1024 -> Q, K, VWo^T
  gemm_qkv<<<dim3(64, 24, 1), blk, 0, stream>>>(xb, Wqkvb, Q, Km, VWot, bq, bk);
  // scores = Q K^T * 0.125, batched: M=N=2048, K=1024
  gemm_bt<<<dim3(16, 16, 4), blk, 0, stream>>>(Q, Km, P, nullptr, 1024, 2048,
                                               S * D, S * D, S * S, 0.125f, 0);
  // softmax over each of 4*2048 rows
  softmax_rows<<<dim3(8192), blk, 0, stream>>>(P);
  // out = P · VWo + bfinal (f32): M=2048, N=1024, K=2048, batched
  gemm_bt<<<dim3(16, 8, 4), blk, 0, stream>>>(P, VWot, out, bfinal, 2048, 1024,
                                              S * S, D * S, S * D, 1.0f, 2);
}